// Round 5
// baseline (343.771 us; speedup 1.0000x reference)
//
#include <hip/hip_runtime.h>

typedef __bf16 bf16;
typedef unsigned int u32;
typedef float f32x4 __attribute__((ext_vector_type(4)));
typedef __bf16 bf16x4 __attribute__((ext_vector_type(4)));
typedef __bf16 bf16x8 __attribute__((ext_vector_type(8)));

#define MFMA(a, b, c) __builtin_amdgcn_mfma_f32_16x16x32_bf16((a), (b), (c), 0, 0, 0)

static constexpr int Bc = 4;      // batch
static constexpr int Sc = 2048;   // seq len
static constexpr int Hc = 16;     // heads
static constexpr int DHc = 64;    // head dim
static constexpr int Dc = 1024;   // model dim
static constexpr int Mc = Bc * Sc; // 8192 rows

// async 16B/lane global->LDS. lp must be wave-uniform; lane i lands at lp+16*i.
__device__ __forceinline__ void load_lds16(const void* gp, void* lp) {
    __builtin_amdgcn_global_load_lds(
        reinterpret_cast<const __attribute__((address_space(1))) u32*>(
            reinterpret_cast<uintptr_t>(gp)),
        reinterpret_cast<__attribute__((address_space(3))) u32*>(
            static_cast<u32>(reinterpret_cast<uintptr_t>(lp))),
        16, 0, 0);
}

// ---------------------------------------------------------------------------
__global__ void fill_diag(float* out, int n) {
    int i = blockIdx.x * 256 + threadIdx.x;
    if (i < n) out[i] = 1000.0f;
}

// ---------------------------------------------------------------------------
// 4x fused 1024x1024 transpose + fp32->bf16: Oi[n][k] = (bf16)Ai[k][n]
// ---------------------------------------------------------------------------
__global__ __launch_bounds__(256) void transpose4(
    const float* __restrict__ A0, const float* __restrict__ A1,
    const float* __restrict__ A2, const float* __restrict__ A3,
    bf16* __restrict__ O0, bf16* __restrict__ O1,
    bf16* __restrict__ O2, bf16* __restrict__ O3) {
    __shared__ bf16 t[32][33];
    const float* in = blockIdx.z == 0 ? A0 : blockIdx.z == 1 ? A1
                    : blockIdx.z == 2 ? A2 : A3;
    bf16* out = blockIdx.z == 0 ? O0 : blockIdx.z == 1 ? O1
              : blockIdx.z == 2 ? O2 : O3;
    int x = blockIdx.x * 32 + threadIdx.x;
#pragma unroll
    for (int j = 0; j < 32; j += 8) {
        int y = blockIdx.y * 32 + threadIdx.y + j;
        t[threadIdx.y + j][threadIdx.x] = (bf16)in[y * 1024 + x];
    }
    __syncthreads();
    int x2 = blockIdx.y * 32 + threadIdx.x;
#pragma unroll
    for (int j = 0; j < 32; j += 8) {
        int y2 = blockIdx.x * 32 + threadIdx.y + j;
        out[y2 * 1024 + x2] = t[threadIdx.x][threadIdx.y + j];
    }
}

// ---------------------------------------------------------------------------
// Fused QKV projection, v5: ONE launch (grid.z=3), A read as FP32 via
// async global_load_lds DMA (round-3's failure was SYNCHRONOUS reg loads;
// this is the async fix), fp32->bf16 conversion at fragment-read time
// (VALU pipe, overlaps MFMA pipe per m114).
//  - deletes the 3 cvt passes + Xin round-trip entirely
//  - 1536 blocks = 6 blocks/CU of work; LDS 48KB -> 3 resident = 12 waves/CU
//    (the m97 occupancy regime; round-4 GEMMs had only 8 waves/CU)
//  - A LDS rows are 128B: both-sides granule-XOR swizzle (same as attn K):
//    LDS granule g of row r holds source granule g^(r&7); read granules
//    (2q)^(r&7) and ^1 form an aligned 32B pair; 2 lanes/granule = free.
// z=0,1 -> [B,H,S,Dh] out; z=2 -> [B,H,Dh,S].
// ---------------------------------------------------------------------------
__global__ __launch_bounds__(256) void gemm_qkv(
    const float* __restrict__ Aq, const float* __restrict__ Ak,
    const float* __restrict__ Av,
    const bf16* __restrict__ Wq, const bf16* __restrict__ Wk,
    const bf16* __restrict__ Wv,
    const float* __restrict__ bq, const float* __restrict__ bk,
    const float* __restrict__ bv,
    bf16* __restrict__ Oq, bf16* __restrict__ Ok, bf16* __restrict__ Ov) {
    __shared__ alignas(16) float As[2][128 * 32];   // fp32 A, swizzled rows
    __shared__ alignas(16) bf16 Bs[2][128 * 32];
    const int z = blockIdx.z;
    const float* A = z == 0 ? Aq : z == 1 ? Ak : Av;
    const bf16* Wt = z == 0 ? Wq : z == 1 ? Wk : Wv;
    const float* bias = z == 0 ? bq : z == 1 ? bk : bv;
    bf16* out = z == 0 ? Oq : z == 1 ? Ok : Ov;
    const bool vmode = (z == 2);

    const int tid = threadIdx.x;
    const int wave = tid >> 6, lane = tid & 63;
    const int quad = lane >> 4, l16 = lane & 15;
    const int m7 = l16 & 7;
    const int wr = (wave >> 1) * 64, wc = (wave & 1) * 64;
    const int id = blockIdx.y * 8 + blockIdx.x;       // bijective XCD swizzle
    const int sw = (id & 7) * 64 + (id >> 3);
    const int row0 = (sw >> 3) * 128, col0 = (sw & 7) * 128;

    // A staging: wave slice = rows [wave*32, wave*32+32). Call j covers rows
    // j*8..j*8+7: lane i -> row j*8+(i>>3), LDS granule i&7, source granule
    // (i&7)^((i>>3)&7)  (inverse swizzle on the per-lane GLOBAL address).
    const int arow = wave * 32 + (lane >> 3);
    const int agr = (lane & 7) ^ ((lane >> 3) & 7);
    const float* gA = &A[(size_t)(row0 + arow) * Dc + agr * 4];
    // B staging (bf16 DMA, linear [128][32])
    const int sr = wave * 32 + (lane >> 2);
    const int sk = (lane & 3) * 8;
    const bf16* gB = &Wt[(size_t)(col0 + sr) * Dc + sk];

#define QSTAGE(BUF, KOFF)                                                    \
    do {                                                                     \
        load_lds16(gA + (KOFF),           &As[BUF][(wave * 32 + 0) * 32]);   \
        load_lds16(gA + (KOFF) + 8 * Dc,  &As[BUF][(wave * 32 + 8) * 32]);   \
        load_lds16(gA + (KOFF) + 16 * Dc, &As[BUF][(wave * 32 + 16) * 32]);  \
        load_lds16(gA + (KOFF) + 24 * Dc, &As[BUF][(wave * 32 + 24) * 32]);  \
        load_lds16(gB + (KOFF), &Bs[BUF][wave * 32 * 32]);                   \
        load_lds16(gB + (KOFF) + 16 * Dc, &Bs[BUF][wave * 32 * 32 + 16 * 32]); \
    } while (0)

    f32x4 acc[4][4];
#pragma unroll
    for (int mi = 0; mi < 4; ++mi)
#pragma unroll
        for (int ni = 0; ni < 4; ++ni)
            acc[mi][ni] = (f32x4){0.f, 0.f, 0.f, 0.f};

    // read-side swizzled granules: source chunk 2q -> LDS granule (2q)^m7
    const int ga = (2 * quad) ^ m7, gb = ga ^ 1;

    QSTAGE(0, 0);
    asm volatile("s_waitcnt vmcnt(0)" ::: "memory");
    __builtin_amdgcn_s_barrier();
    __builtin_amdgcn_sched_barrier(0);

    int cur = 0;
#pragma unroll 1
    for (int i = 0; i < Dc / 32; ++i) {
        if (i + 1 < Dc / 32) QSTAGE(cur ^ 1, (i + 1) * 32);

        bf16x8 af[4], bfr[4];
#pragma unroll
        for (int mi = 0; mi < 4; ++mi) {
            const int row = wr + mi * 16 + l16;
            f32x4 a0 = *(const f32x4*)&As[cur][row * 32 + ga * 4];
            f32x4 a1 = *(const f32x4*)&As[cur][row * 32 + gb * 4];
#pragma unroll
            for (int j = 0; j < 4; ++j) {
                af[mi][j] = (bf16)a0[j];
                af[mi][j + 4] = (bf16)a1[j];
            }
        }
#pragma unroll
        for (int ni = 0; ni < 4; ++ni)
            bfr[ni] = *(const bf16x8*)&Bs[cur][(wc + ni * 16 + l16) * 32 + quad * 8];
#pragma unroll
        for (int mi = 0; mi < 4; ++mi)
#pragma unroll
            for (int ni = 0; ni < 4; ++ni)
                acc[mi][ni] = MFMA(af[mi], bfr[ni], acc[mi][ni]);

        // next tile's DMA had the whole compute phase to land
        asm volatile("s_waitcnt vmcnt(0)" ::: "memory");
        __builtin_amdgcn_s_barrier();
        __builtin_amdgcn_sched_barrier(0);
        cur ^= 1;
    }
#undef QSTAGE

    // epilogue: C/D layout col=lane&15, row=quad*4+reg
#pragma unroll
    for (int mi = 0; mi < 4; ++mi) {
#pragma unroll
        for (int ni = 0; ni < 4; ++ni) {
            int col = col0 + wc + ni * 16 + l16;
            float bv = bias[col];
#pragma unroll
            for (int r = 0; r < 4; ++r) {
                int row = row0 + wr + mi * 16 + quad * 4 + r;
                float v = acc[mi][ni][r] + bv;
                int b = row >> 11, s = row & (Sc - 1);
                int h = col >> 6, dh = col & (DHc - 1);
                size_t off;
                if (!vmode)
                    off = (((size_t)(b * Hc + h) * Sc + s) << 6) + dh;
                else
                    off = (((size_t)(b * Hc + h) * DHc + dh) << 11) + s;
                out[off] = (bf16)v;
            }
        }
    }
}

// ---------------------------------------------------------------------------
// Output projection: C[M,N] = A[M,K] @ Wt[N,K]^T + bias[N]; bf16 A via DMA,
// fp32 out row-major. m97 tile + XCD swizzle + 3-buffer counted-vmcnt
// pipeline (round-4 measured version, unchanged).
// ---------------------------------------------------------------------------
__global__ __launch_bounds__(256) void gemm_bt(const bf16* __restrict__ A,
                                               const bf16* __restrict__ Wt,
                                               const float* __restrict__ bias,
                                               float* __restrict__ out,
                                               int M, int N, int K) {
    __shared__ alignas(16) bf16 As[3][128 * 32];
    __shared__ alignas(16) bf16 Bs[3][128 * 32];
    const int tid = threadIdx.x;
    const int wave = tid >> 6, lane = tid & 63;
    const int quad = lane >> 4, l16 = lane & 15;
    const int wr = (wave >> 1) * 64, wc = (wave & 1) * 64;
    const int id = blockIdx.y * 8 + blockIdx.x;
    const int sw = (id & 7) * 64 + (id >> 3);
    const int row0 = (sw >> 3) * 128, col0 = (sw & 7) * 128;

    const int sr = wave * 32 + (lane >> 2);
    const int sk = (lane & 3) * 8;
    const bf16* gA = &A[(size_t)(row0 + sr) * K + sk];
    const bf16* gB = &Wt[(size_t)(col0 + sr) * K + sk];
    const int wo = wave * 32 * 32;

#define GSTAGE(BUF, KOFF)                                                   \
    do {                                                                    \
        load_lds16(gA + (KOFF), &As[BUF][wo]);                              \
        load_lds16(gA + (KOFF) + 16 * K, &As[BUF][wo + 16 * 32]);           \
        load_lds16(gB + (KOFF), &Bs[BUF][wo]);                              \
        load_lds16(gB + (KOFF) + 16 * K, &Bs[BUF][wo + 16 * 32]);           \
    } while (0)

    f32x4 acc[4][4];
#pragma unroll
    for (int mi = 0; mi < 4; ++mi)
#pragma unroll
        for (int ni = 0; ni < 4; ++ni)
            acc[mi][ni] = (f32x4){0.f, 0.f, 0.f, 0.f};

    const int nk = K / 32;
    GSTAGE(0, 0);
    GSTAGE(1, 32);
    asm volatile("s_waitcnt vmcnt(4)" ::: "memory");
    __builtin_amdgcn_s_barrier();
    __builtin_amdgcn_sched_barrier(0);

    int cur = 0, nxt = 2;
#pragma unroll 1
    for (int i = 0; i < nk; ++i) {
        if (i + 2 < nk) GSTAGE(nxt, (i + 2) * 32);

        bf16x8 af[4], bf_[4];
#pragma unroll
        for (int mi = 0; mi < 4; ++mi)
            af[mi] = *(const bf16x8*)&As[cur][(wr + mi * 16 + l16) * 32 + quad * 8];
#pragma unroll
        for (int ni = 0; ni < 4; ++ni)
            bf_[ni] = *(const bf16x8*)&Bs[cur][(wc + ni * 16 + l16) * 32 + quad * 8];
#pragma unroll
        for (int mi = 0; mi < 4; ++mi)
#pragma unroll
            for (int ni = 0; ni < 4; ++ni)
                acc[mi][ni] = MFMA(af[mi], bf_[ni], acc[mi][ni]);

        if (i + 2 < nk) asm volatile("s_waitcnt vmcnt(4)" ::: "memory");
        else            asm volatile("s_waitcnt vmcnt(0)" ::: "memory");
        __builtin_amdgcn_s_barrier();
        __builtin_amdgcn_sched_barrier(0);
        cur = (cur == 2) ? 0 : cur + 1;
        nxt = (nxt == 2) ? 0 : nxt + 1;
    }
#undef GSTAGE

#pragma unroll
    for (int mi = 0; mi < 4; ++mi) {
#pragma unroll
        for (int ni = 0; ni < 4; ++ni) {
            int col = col0 + wc + ni * 16 + l16;
            float bv = bias[col];
#pragma unroll
            for (int r = 0; r < 4; ++r) {
                int row = row0 + wr + mi * 16 + quad * 4 + r;
                out[(size_t)row * N + col] = acc[mi][ni][r] + bv;
            }
        }
    }
}

// ---------------------------------------------------------------------------
// Flash-style causal attention, v5 (measured 64.0us twice; unchanged).
// Double-buffered direct-to-LDS pipeline, one barrier per tile:
//   STAGE(buf^1, t+1) ; compute(buf) ; asm vmcnt(0) ; s_barrier
// Block = q-tile pair (15-p, p): every block does exactly 34 tile-iters;
// grid 512 = exactly 2 blocks/CU. LDS 59392B; launch_bounds(256,2).
// Q,K: [B,H,S,Dh] bf16; Vt: [B,H,Dh,S] bf16; mask: [B,S] int32
// ---------------------------------------------------------------------------
static constexpr int LPP = 72; // Ps padded row stride (elements)
static constexpr float CEXP = 1.4426950408889634f / 4096.0f; // log2(e)/Dh^2

__global__ __launch_bounds__(256, 2) void attn_fwd(const bf16* __restrict__ Q,
                                                   const bf16* __restrict__ K,
                                                   const bf16* __restrict__ Vt,
                                                   const int* __restrict__ mask,
                                                   bf16* __restrict__ Ctx) {
    __shared__ alignas(16) bf16 Ks[2][64 * 64];   // [buf][row*64+g*8] swizzled
    __shared__ alignas(16) bf16 Vs[2][64 * 64];   // [buf][dh*64+g*8] swizzled
    __shared__ alignas(16) bf16 Ps[4][32 * LPP];  // per-wave P[q][key]
    __shared__ alignas(16) float msk_all[Sc];     // whole pad-mask row, once

    const int tid = threadIdx.x;
    const int wave = tid >> 6, lane = tid & 63;
    const int quad = lane >> 4, l16 = lane & 15;
    const int id = blockIdx.y * 8 + blockIdx.x;
    const int sw = (id & 7) * 64 + (id >> 3);
    const int bh = sw >> 3, p = sw & 7;
    const int b = bh >> 4, h = bh & 15;

    {
        const int i = tid * 8;
        int4 m0 = *(const int4*)&mask[b * Sc + i];
        int4 m1 = *(const int4*)&mask[b * Sc + i + 4];
        f32x4 f0 = {m0.x ? 0.f : -1e30f, m0.y ? 0.f : -1e30f,
                    m0.z ? 0.f : -1e30f, m0.w ? 0.f : -1e30f};
        f32x4 f1 = {m1.x ? 0.f : -1e30f, m1.y ? 0.f : -1e30f,
                    m1.z ? 0.f : -1e30f, m1.w ? 0.f : -1e30f};
        *(f32x4*)&msk_all[i] = f0;
        *(f32x4*)&msk_all[i + 4] = f1;
    }

    const int swz = ((lane & 7) ^ (lane >> 3)) << 4;        // source byte XOR
    const int rA = wave * 16 + (lane >> 3);                  // local row, j=0
    const char* gK0 = (const char*)K + (size_t)bh * Sc * (DHc * 2)
                    + (size_t)rA * 128 + swz;
    const char* gV0 = (const char*)Vt + (size_t)bh * DHc * (Sc * 2)
                    + (size_t)rA * (Sc * 2) + swz;
    bf16* lK0 = &Ks[0][(wave * 16) * 64];
    bf16* lV0 = &Vs[0][(wave * 16) * 64];

    const int m7 = l16 & 7;
    const int gsw0 = ((0 + quad) ^ m7) * 8;
    const int gsw1 = ((4 + quad) ^ m7) * 8;

#define STAGE(BUF, KB)                                                        \
    do {                                                                      \
        load_lds16((const bf16*)(gK0 + (size_t)(KB) * 128),                   \
                   lK0 + (BUF) * (64 * 64));                                  \
        load_lds16((const bf16*)(gK0 + (size_t)(KB) * 128 + 1024),            \
                   lK0 + (BUF) * (64 * 64) + 8 * 64);                         \
        load_lds16((const bf16*)(gV0 + (size_t)(KB) * 2),                     \
                   lV0 + (BUF) * (64 * 64));                                  \
        load_lds16((const bf16*)(gV0 + (size_t)(KB) * 2 + 8 * 4096),          \
                   lV0 + (BUF) * (64 * 64) + 8 * 64);                         \
    } while (0)

#pragma unroll 1
    for (int pass = 0; pass < 2; ++pass) {
        const int qt = pass ? p : 15 - p;
        const int qr0 = qt * 128 + wave * 32;
        const int qmax = qr0 + 31;

        bf16x8 bq[2][2];
#pragma unroll
        for (int mt = 0; mt < 2; ++mt) {
            const size_t qoff = ((size_t)bh * Sc + qr0 + mt * 16 + l16) * DHc;
            bq[mt][0] = *(const bf16x8*)&Q[qoff + quad * 8];
            bq[mt][1] = *(const bf16x8*)&Q[qoff + 32 + quad * 8];
        }

        f32x4 accO[2][4];
#pragma unroll
        for (int mt = 0; mt < 2; ++mt)
#pragma unroll
            for (int oi = 0; oi < 4; ++oi) accO[mt][oi] = (f32x4){0.f, 0.f, 0.f, 0.f};
        float l_part[2] = {0.f, 0.f};

        const int nkt = 2 * qt + 2;
        STAGE(0, 0);
        __syncthreads();
        int cur = 0;
#pragma unroll 1
        for (int kt = 0; kt < nkt; ++kt) {
            const int kb = kt * 64;
            if (kt + 1 < nkt) STAGE(cur ^ 1, kb + 64);
            if (kb <= qmax) {
                const bf16* Kb_ = &Ks[cur][0];
                const bf16* Vb_ = &Vs[cur][0];

                f32x4 st[2][4];
                __builtin_amdgcn_s_setprio(1);
#pragma unroll
                for (int kti = 0; kti < 4; ++kti) {
                    bf16x8 ak0 = *(const bf16x8*)&Kb_[(kti * 16 + l16) * 64 + gsw0];
                    bf16x8 ak1 = *(const bf16x8*)&Kb_[(kti * 16 + l16) * 64 + gsw1];
#pragma unroll
                    for (int mt = 0; mt < 2; ++mt) {
                        f32x4 z = {0.f, 0.f, 0.f, 0.f};
                        z = MFMA(ak0, bq[mt][0], z);
                        z = MFMA(ak1, bq[mt][1], z);
                        st[mt][kti] = z;
                    }
                }
                __builtin_amdgcn_s_setprio(0);

#define SM_TILE(DIAG)                                                          \
                _Pragma("unroll")                                              \
                for (int mt = 0; mt < 2; ++mt) {                               \
                    _Pragma("unroll")                                          \
                    for (int kti = 0; kti < 4; ++kti) {                        \
                        const f32x4 mkv =                                      \
                            *(const f32x4*)&msk_all[kb + kti * 16 + quad * 4]; \
                        const int cbase =                                      \
                            kb + kti * 16 + quad * 4 - (qr0 + mt * 16);        \
                        bf16x4 pv;                                             \
                        _Pragma("unroll")                                      \
                        for (int r = 0; r < 4; ++r) {                          \
                            float s = st[mt][kti][r] * CEXP + mkv[r];          \
                            if (DIAG) s = (cbase + r > l16) ? -1e30f : s;      \
                            float p_ = __builtin_amdgcn_exp2f(s);              \
                            l_part[mt] += p_;                                  \
                            pv[r] = (bf16)p_;                                  \
                        }                                                      \
                        *(bf16x4*)&Ps[wave][(mt * 16 + l16) * LPP +            \
                                            kti * 16 + quad * 4] = pv;         \
                    }                                                          \
                }
                if (kb + 63 > qr0) { SM_TILE(1) } else { SM_TILE(0) }
#undef SM_TILE

                __builtin_amdgcn_s_setprio(1);
#pragma unroll
                for (int kk = 0; kk < 2; ++kk) {
                    bf16x8 ap0 = *(const bf16x8*)&Ps[wave][(l16) * LPP + kk * 32 + quad * 8];
                    bf16x8 ap1 = *(const bf16x8*)&Ps[wave][(16 + l16) * LPP + kk * 32 + quad * 8];
                    const int vg = kk ? gsw1 : gsw0;
#pragma unroll
                    for (int oi = 0; oi < 4; ++oi) {
                        bf16x8 bv = *(const bf16x8*)&Vb_[(oi * 16 + l16) * 64 + vg];
                        accO[0][oi] = MFMA(ap0, bv, accO[0][oi]);
                        accO[1][oi] = MFMA(ap1, bv, accO[1][oi]);
                    }
                }
                __builtin_amdgcn_s_setprio(0);
            }
            asm volatile("s_waitcnt vmcnt(0)" ::: "memory");
            __builtin_amdgcn_s_barrier();
            __builtin_amdgcn_sched_barrier(0);
            cur ^= 1;
        }

        float lvi[2][4];
#pragma unroll
        for (int mt = 0; mt < 2; ++mt) {
            float l = l_part[mt];
            l += __shfl_xor(l, 16);
            l += __shfl_xor(l, 32);
#pragma unroll
            for (int r = 0; r < 4; ++r)
                lvi[mt][r] = __builtin_amdgcn_rcpf(__shfl(l, quad * 4 + r));
        }
#pragma unroll
        for (int mt = 0; mt < 2; ++mt)
#pragma unroll
            for (int oi = 0; oi < 4; ++oi)
#pragma unroll
                for (int r = 0; r < 4; ++r) {
                    int s = qr0 + mt * 16 + quad * 4 + r;
                    int dh = oi * 16 + l16;
                    float v = accO[mt][oi][r] * lvi[mt][r];
                    Ctx[((size_t)b * Sc + s) * Dc + h * DHc + dh] = (bf16)v;
                }
    }
#undef STAGE
}

// ---------------------------------------------------------------------------
extern "C" void kernel_launch(void* const* d_in, const int* in_sizes, int n_in,
                              void* d_out, int out_size, void* d_ws, size_t ws_size,
                              hipStream_t stream) {
    const float* query = (const float*)d_in[0];
    const float* key_i = (const float*)d_in[1];
    const float* value = (const float*)d_in[2];
    const int* mask    = (const int*)d_in[3];
    const float* W_q = (const float*)d_in[4];
    const float* b_q = (const float*)d_in[5];
    const float* W_k = (const float*)d_in[6];
    const float* b_k = (const float*)d_in[7];
    const float* W_v = (const float*)d_in[8];
    const float* b_v = (const float*)d_in[9];
    const float* W_o = (const float*)d_in[10];
    const float* b_o = (const float*)d_in[11];
    float* out = (float*)d_out;

    const size_t MB = 1024 * 1024;
    const size_t NEED = 72 * MB;
    if (ws_size < NEED) {
        fill_diag<<<(out_size + 255) / 256, 256, 0, stream>>>(out, out_size);
        return;
    }

    char* ws = (char*)d_ws;
    bf16* WtQ = (bf16*)(ws + 0 * MB);   // 2 MB each
    bf16* WtK = (bf16*)(ws + 2 * MB);
    bf16* WtV = (bf16*)(ws + 4 * MB);
    bf16* WtO = (bf16*)(ws + 6 * MB);
    bf16* Qb  = (bf16*)(ws + 8 * MB);   // [B,H,S,Dh]  16 MB
    bf16* Kb  = (bf16*)(ws + 24 * MB);  // [B,H,S,Dh]  16 MB
    bf16* Vtb = (bf16*)(ws + 40 * MB);  // [B,H,Dh,S]  16 MB
    bf16* Ctx = (bf16*)(ws + 56 * MB);  // [B,S,D]     16 MB

    transpose4<<<dim3(32, 32, 4), dim3(32, 8), 0, stream>>>(
        W_q, W_k, W_v, W_o, WtQ, WtK, WtV, WtO);

    gemm_qkv<<<dim3(8, 64, 3), 256, 0, stream>>>(
        query, key_i, value, WtQ, WtK, WtV, b_q, b_k, b_v, Qb, Kb, Vtb);

    attn_fwd<<<dim3(8, Bc * Hc), 256, 0, stream>>>(Qb, Kb, Vtb, mask, Ctx);

    gemm_bt<<<dim3(8, 64), 256, 0, stream>>>(Ctx, WtO, b_o, out, Mc, Dc, Dc);
}

// Round 6
// 315.655 us; speedup vs baseline: 1.0891x; 1.0891x over previous
//
#include <hip/hip_runtime.h>

typedef __bf16 bf16;
typedef unsigned int u32;
typedef float f32x4 __attribute__((ext_vector_type(4)));
typedef __bf16 bf16x4 __attribute__((ext_vector_type(4)));
typedef __bf16 bf16x8 __attribute__((ext_vector_type(8)));

#define MFMA(a, b, c) __builtin_amdgcn_mfma_f32_16x16x32_bf16((a), (b), (c), 0, 0, 0)

static constexpr int Bc = 4;      // batch
static constexpr int Sc = 2048;   // seq len
static constexpr int Hc = 16;     // heads
static constexpr int DHc = 64;    // head dim
static constexpr int Dc = 1024;   // model dim
static constexpr int Mc = Bc * Sc; // 8192 rows

// async 16B/lane global->LDS. lp must be wave-uniform; lane i lands at lp+16*i.
__device__ __forceinline__ void load_lds16(const void* gp, void* lp) {
    __builtin_amdgcn_global_load_lds(
        reinterpret_cast<const __attribute__((address_space(1))) u32*>(
            reinterpret_cast<uintptr_t>(gp)),
        reinterpret_cast<__attribute__((address_space(3))) u32*>(
            static_cast<u32>(reinterpret_cast<uintptr_t>(lp))),
        16, 0, 0);
}

// ---------------------------------------------------------------------------
__global__ void fill_diag(float* out, int n) {
    int i = blockIdx.x * 256 + threadIdx.x;
    if (i < n) out[i] = 1000.0f;
}

// ---------------------------------------------------------------------------
// fp32 -> bf16 bulk convert for ALL THREE inputs in one launch (grid.y picks
// the tensor; 2 fewer launch gaps than 3 separate cvt dispatches).
// ---------------------------------------------------------------------------
__global__ __launch_bounds__(256) void cvt3(const float* __restrict__ q,
                                            const float* __restrict__ k,
                                            const float* __restrict__ v,
                                            bf16* __restrict__ oq,
                                            bf16* __restrict__ ok,
                                            bf16* __restrict__ ov) {
    const int z = blockIdx.y;
    const float* in = z == 0 ? q : z == 1 ? k : v;
    bf16* out = z == 0 ? oq : z == 1 ? ok : ov;
    int i = (blockIdx.x * 256 + threadIdx.x) * 8;
    f32x4 a = *(const f32x4*)&in[i];
    f32x4 b = *(const f32x4*)&in[i + 4];
    bf16x8 w;
#pragma unroll
    for (int j = 0; j < 4; ++j) { w[j] = (bf16)a[j]; w[j + 4] = (bf16)b[j]; }
    *(bf16x8*)&out[i] = w;
}

// ---------------------------------------------------------------------------
// 4x fused 1024x1024 transpose + fp32->bf16: Oi[n][k] = (bf16)Ai[k][n]
// ---------------------------------------------------------------------------
__global__ __launch_bounds__(256) void transpose4(
    const float* __restrict__ A0, const float* __restrict__ A1,
    const float* __restrict__ A2, const float* __restrict__ A3,
    bf16* __restrict__ O0, bf16* __restrict__ O1,
    bf16* __restrict__ O2, bf16* __restrict__ O3) {
    __shared__ bf16 t[32][33];
    const float* in = blockIdx.z == 0 ? A0 : blockIdx.z == 1 ? A1
                    : blockIdx.z == 2 ? A2 : A3;
    bf16* out = blockIdx.z == 0 ? O0 : blockIdx.z == 1 ? O1
              : blockIdx.z == 2 ? O2 : O3;
    int x = blockIdx.x * 32 + threadIdx.x;
#pragma unroll
    for (int j = 0; j < 32; j += 8) {
        int y = blockIdx.y * 32 + threadIdx.y + j;
        t[threadIdx.y + j][threadIdx.x] = (bf16)in[y * 1024 + x];
    }
    __syncthreads();
    int x2 = blockIdx.y * 32 + threadIdx.x;
#pragma unroll
    for (int j = 0; j < 32; j += 8) {
        int y2 = blockIdx.x * 32 + threadIdx.y + j;
        out[y2 * 1024 + x2] = t[threadIdx.x][threadIdx.y + j];
    }
}

// ---------------------------------------------------------------------------
// C[M,N] = A[M,K] @ Wt[N,K]^T + bias[N]; bf16 in, fp32 accum, TOUT out.
// Round-4 measured version (total 319.6us), unchanged: m97 tile + bijective
// XCD swizzle + T3/T4 3-buffer counted-vmcnt pipeline (stage i+1 in flight
// across the barrier; never drain to 0 in the main loop).
// MODE 0: out row-major [M,N]; MODE 1: [B,H,S,Dh]; MODE 2: [B,H,Dh,S]
// ---------------------------------------------------------------------------
template <int MODE, typename TOUT>
__global__ __launch_bounds__(256) void gemm_bt(const bf16* __restrict__ A,
                                               const bf16* __restrict__ Wt,
                                               const float* __restrict__ bias,
                                               TOUT* __restrict__ out,
                                               int M, int N, int K) {
    __shared__ alignas(16) bf16 As[3][128 * 32];
    __shared__ alignas(16) bf16 Bs[3][128 * 32];
    const int tid = threadIdx.x;
    const int wave = tid >> 6, lane = tid & 63;
    const int quad = lane >> 4, l16 = lane & 15;
    const int wr = (wave >> 1) * 64, wc = (wave & 1) * 64;
    const int id = blockIdx.y * 8 + blockIdx.x;       // bijective XCD swizzle
    const int sw = (id & 7) * 64 + (id >> 3);
    const int row0 = (sw >> 3) * 128, col0 = (sw & 7) * 128;

    const int sr = wave * 32 + (lane >> 2);
    const int sk = (lane & 3) * 8;
    const bf16* gA = &A[(size_t)(row0 + sr) * K + sk];
    const bf16* gB = &Wt[(size_t)(col0 + sr) * K + sk];
    const int wo = wave * 32 * 32;

#define GSTAGE(BUF, KOFF)                                                   \
    do {                                                                    \
        load_lds16(gA + (KOFF), &As[BUF][wo]);                              \
        load_lds16(gA + (KOFF) + 16 * K, &As[BUF][wo + 16 * 32]);           \
        load_lds16(gB + (KOFF), &Bs[BUF][wo]);                              \
        load_lds16(gB + (KOFF) + 16 * K, &Bs[BUF][wo + 16 * 32]);           \
    } while (0)

    f32x4 acc[4][4];
#pragma unroll
    for (int mi = 0; mi < 4; ++mi)
#pragma unroll
        for (int ni = 0; ni < 4; ++ni)
            acc[mi][ni] = (f32x4){0.f, 0.f, 0.f, 0.f};

    const int nk = K / 32;
    GSTAGE(0, 0);
    GSTAGE(1, 32);
    asm volatile("s_waitcnt vmcnt(4)" ::: "memory");  // stage 0 done
    __builtin_amdgcn_s_barrier();
    __builtin_amdgcn_sched_barrier(0);

    int cur = 0, nxt = 2;
#pragma unroll 1
    for (int i = 0; i < nk; ++i) {
        if (i + 2 < nk) GSTAGE(nxt, (i + 2) * 32);    // deep prefetch

        bf16x8 af[4], bf_[4];
#pragma unroll
        for (int mi = 0; mi < 4; ++mi)
            af[mi] = *(const bf16x8*)&As[cur][(wr + mi * 16 + l16) * 32 + quad * 8];
#pragma unroll
        for (int ni = 0; ni < 4; ++ni)
            bf_[ni] = *(const bf16x8*)&Bs[cur][(wc + ni * 16 + l16) * 32 + quad * 8];
#pragma unroll
        for (int mi = 0; mi < 4; ++mi)
#pragma unroll
            for (int ni = 0; ni < 4; ++ni)
                acc[mi][ni] = MFMA(af[mi], bf_[ni], acc[mi][ni]);

        // stage i+1 must be done for next iter; stage i+2 stays in flight
        if (i + 2 < nk) asm volatile("s_waitcnt vmcnt(4)" ::: "memory");
        else            asm volatile("s_waitcnt vmcnt(0)" ::: "memory");
        __builtin_amdgcn_s_barrier();
        __builtin_amdgcn_sched_barrier(0);
        cur = (cur == 2) ? 0 : cur + 1;
        nxt = (nxt == 2) ? 0 : nxt + 1;
    }
#undef GSTAGE

    // epilogue: C/D layout col=lane&15, row=quad*4+reg
#pragma unroll
    for (int mi = 0; mi < 4; ++mi) {
#pragma unroll
        for (int ni = 0; ni < 4; ++ni) {
            int col = col0 + wc + ni * 16 + l16;
            float bv = bias[col];
#pragma unroll
            for (int r = 0; r < 4; ++r) {
                int row = row0 + wr + mi * 16 + quad * 4 + r;
                float v = acc[mi][ni][r] + bv;
                size_t off;
                if (MODE == 0) {
                    off = (size_t)row * N + col;
                } else {
                    int b = row >> 11, s = row & (Sc - 1); // S = 2048
                    int h = col >> 6, dh = col & (DHc - 1);
                    if (MODE == 1)
                        off = (((size_t)(b * Hc + h) * Sc + s) << 6) + dh;
                    else
                        off = (((size_t)(b * Hc + h) * DHc + dh) << 11) + s;
                }
                out[off] = (TOUT)v;
            }
        }
    }
}

// ---------------------------------------------------------------------------
// Flash-style causal attention, v5 (measured 64.0us in rounds 2 and 4;
// unchanged). Double-buffered direct-to-LDS pipeline, one barrier per tile:
//   STAGE(buf^1, t+1) ; compute(buf) ; asm vmcnt(0) ; s_barrier
// Block = q-tile pair (15-p, p): every block does exactly 34 tile-iters;
// grid 512 = exactly 2 blocks/CU. LDS 59392B; launch_bounds(256,2).
// Q,K: [B,H,S,Dh] bf16; Vt: [B,H,Dh,S] bf16; mask: [B,S] int32
// ---------------------------------------------------------------------------
static constexpr int LPP = 72; // Ps padded row stride (elements)
static constexpr float CEXP = 1.4426950408889634f / 4096.0f; // log2(e)/Dh^2

__global__ __launch_bounds__(256, 2) void attn_fwd(const bf16* __restrict__ Q,
                                                   const bf16* __restrict__ K,
                                                   const bf16* __restrict__ Vt,
                                                   const int* __restrict__ mask,
                                                   bf16* __restrict__ Ctx) {
    __shared__ alignas(16) bf16 Ks[2][64 * 64];   // [buf][row*64+g*8] swizzled
    __shared__ alignas(16) bf16 Vs[2][64 * 64];   // [buf][dh*64+g*8] swizzled
    __shared__ alignas(16) bf16 Ps[4][32 * LPP];  // per-wave P[q][key]
    __shared__ alignas(16) float msk_all[Sc];     // whole pad-mask row, once

    const int tid = threadIdx.x;
    const int wave = tid >> 6, lane = tid & 63;
    const int quad = lane >> 4, l16 = lane & 15;
    const int id = blockIdx.y * 8 + blockIdx.x;
    const int sw = (id & 7) * 64 + (id >> 3);
    const int bh = sw >> 3, p = sw & 7;
    const int b = bh >> 4, h = bh & 15;

    {
        const int i = tid * 8;
        int4 m0 = *(const int4*)&mask[b * Sc + i];
        int4 m1 = *(const int4*)&mask[b * Sc + i + 4];
        f32x4 f0 = {m0.x ? 0.f : -1e30f, m0.y ? 0.f : -1e30f,
                    m0.z ? 0.f : -1e30f, m0.w ? 0.f : -1e30f};
        f32x4 f1 = {m1.x ? 0.f : -1e30f, m1.y ? 0.f : -1e30f,
                    m1.z ? 0.f : -1e30f, m1.w ? 0.f : -1e30f};
        *(f32x4*)&msk_all[i] = f0;
        *(f32x4*)&msk_all[i + 4] = f1;
    }

    const int swz = ((lane & 7) ^ (lane >> 3)) << 4;        // source byte XOR
    const int rA = wave * 16 + (lane >> 3);                  // local row, j=0
    const char* gK0 = (const char*)K + (size_t)bh * Sc * (DHc * 2)
                    + (size_t)rA * 128 + swz;
    const char* gV0 = (const char*)Vt + (size_t)bh * DHc * (Sc * 2)
                    + (size_t)rA * (Sc * 2) + swz;
    bf16* lK0 = &Ks[0][(wave * 16) * 64];
    bf16* lV0 = &Vs[0][(wave * 16) * 64];

    const int m7 = l16 & 7;
    const int gsw0 = ((0 + quad) ^ m7) * 8;
    const int gsw1 = ((4 + quad) ^ m7) * 8;

#define STAGE(BUF, KB)                                                        \
    do {                                                                      \
        load_lds16((const bf16*)(gK0 + (size_t)(KB) * 128),                   \
                   lK0 + (BUF) * (64 * 64));                                  \
        load_lds16((const bf16*)(gK0 + (size_t)(KB) * 128 + 1024),            \
                   lK0 + (BUF) * (64 * 64) + 8 * 64);                         \
        load_lds16((const bf16*)(gV0 + (size_t)(KB) * 2),                     \
                   lV0 + (BUF) * (64 * 64));                                  \
        load_lds16((const bf16*)(gV0 + (size_t)(KB) * 2 + 8 * 4096),          \
                   lV0 + (BUF) * (64 * 64) + 8 * 64);                         \
    } while (0)

#pragma unroll 1
    for (int pass = 0; pass < 2; ++pass) {
        const int qt = pass ? p : 15 - p;
        const int qr0 = qt * 128 + wave * 32;
        const int qmax = qr0 + 31;

        bf16x8 bq[2][2];
#pragma unroll
        for (int mt = 0; mt < 2; ++mt) {
            const size_t qoff = ((size_t)bh * Sc + qr0 + mt * 16 + l16) * DHc;
            bq[mt][0] = *(const bf16x8*)&Q[qoff + quad * 8];
            bq[mt][1] = *(const bf16x8*)&Q[qoff + 32 + quad * 8];
        }

        f32x4 accO[2][4];
#pragma unroll
        for (int mt = 0; mt < 2; ++mt)
#pragma unroll
            for (int oi = 0; oi < 4; ++oi) accO[mt][oi] = (f32x4){0.f, 0.f, 0.f, 0.f};
        float l_part[2] = {0.f, 0.f};

        const int nkt = 2 * qt + 2;
        STAGE(0, 0);
        __syncthreads();
        int cur = 0;
#pragma unroll 1
        for (int kt = 0; kt < nkt; ++kt) {
            const int kb = kt * 64;
            if (kt + 1 < nkt) STAGE(cur ^ 1, kb + 64);
            if (kb <= qmax) {
                const bf16* Kb_ = &Ks[cur][0];
                const bf16* Vb_ = &Vs[cur][0];

                f32x4 st[2][4];
                __builtin_amdgcn_s_setprio(1);
#pragma unroll
                for (int kti = 0; kti < 4; ++kti) {
                    bf16x8 ak0 = *(const bf16x8*)&Kb_[(kti * 16 + l16) * 64 + gsw0];
                    bf16x8 ak1 = *(const bf16x8*)&Kb_[(kti * 16 + l16) * 64 + gsw1];
#pragma unroll
                    for (int mt = 0; mt < 2; ++mt) {
                        f32x4 z = {0.f, 0.f, 0.f, 0.f};
                        z = MFMA(ak0, bq[mt][0], z);
                        z = MFMA(ak1, bq[mt][1], z);
                        st[mt][kti] = z;
                    }
                }
                __builtin_amdgcn_s_setprio(0);

#define SM_TILE(DIAG)                                                          \
                _Pragma("unroll")                                              \
                for (int mt = 0; mt < 2; ++mt) {                               \
                    _Pragma("unroll")                                          \
                    for (int kti = 0; kti < 4; ++kti) {                        \
                        const f32x4 mkv =                                      \
                            *(const f32x4*)&msk_all[kb + kti * 16 + quad * 4]; \
                        const int cbase =                                      \
                            kb + kti * 16 + quad * 4 - (qr0 + mt * 16);        \
                        bf16x4 pv;                                             \
                        _Pragma("unroll")                                      \
                        for (int r = 0; r < 4; ++r) {                          \
                            float s = st[mt][kti][r] * CEXP + mkv[r];          \
                            if (DIAG) s = (cbase + r > l16) ? -1e30f : s;      \
                            float p_ = __builtin_amdgcn_exp2f(s);              \
                            l_part[mt] += p_;                                  \
                            pv[r] = (bf16)p_;                                  \
                        }                                                      \
                        *(bf16x4*)&Ps[wave][(mt * 16 + l16) * LPP +            \
                                            kti * 16 + quad * 4] = pv;         \
                    }                                                          \
                }
                if (kb + 63 > qr0) { SM_TILE(1) } else { SM_TILE(0) }
#undef SM_TILE

                __builtin_amdgcn_s_setprio(1);
#pragma unroll
                for (int kk = 0; kk < 2; ++kk) {
                    bf16x8 ap0 = *(const bf16x8*)&Ps[wave][(l16) * LPP + kk * 32 + quad * 8];
                    bf16x8 ap1 = *(const bf16x8*)&Ps[wave][(16 + l16) * LPP + kk * 32 + quad * 8];
                    const int vg = kk ? gsw1 : gsw0;
#pragma unroll
                    for (int oi = 0; oi < 4; ++oi) {
                        bf16x8 bv = *(const bf16x8*)&Vb_[(oi * 16 + l16) * 64 + vg];
                        accO[0][oi] = MFMA(ap0, bv, accO[0][oi]);
                        accO[1][oi] = MFMA(ap1, bv, accO[1][oi]);
                    }
                }
                __builtin_amdgcn_s_setprio(0);
            }
            asm volatile("s_waitcnt vmcnt(0)" ::: "memory");
            __builtin_amdgcn_s_barrier();
            __builtin_amdgcn_sched_barrier(0);
            cur ^= 1;
        }

        float lvi[2][4];
#pragma unroll
        for (int mt = 0; mt < 2; ++mt) {
            float l = l_part[mt];
            l += __shfl_xor(l, 16);
            l += __shfl_xor(l, 32);
#pragma unroll
            for (int r = 0; r < 4; ++r)
                lvi[mt][r] = __builtin_amdgcn_rcpf(__shfl(l, quad * 4 + r));
        }
#pragma unroll
        for (int mt = 0; mt < 2; ++mt)
#pragma unroll
            for (int oi = 0; oi < 4; ++oi)
#pragma unroll
                for (int r = 0; r < 4; ++r) {
                    int s = qr0 + mt * 16 + quad * 4 + r;
                    int dh = oi * 16 + l16;
                    float v = accO[mt][oi][r] * lvi[mt][r];
                    Ctx[((size_t)b * Sc + s) * Dc + h * DHc + dh] = (bf16)v;
                }
    }
#undef STAGE
}

// ---------------------------------------------------------------------------
// Workspace plan (72 MB, stream-serial so region reuse is race-free):
//   0- 8: WtQ,WtK,WtV,WtO   (2 MB each)
//   8-24: Xq   -> dead after gemm_q  -> Kb
//  24-40: Xk   -> dead after gemm_k  -> Vtb
//  40-56: Xv   -> dead after gemm_v  -> Ctx
//  56-72: Qb
// Launch graph (7 launches, was 9): transpose4; cvt3; gemm_q; gemm_k;
// gemm_v; attn; gemm_o.
// ---------------------------------------------------------------------------
extern "C" void kernel_launch(void* const* d_in, const int* in_sizes, int n_in,
                              void* d_out, int out_size, void* d_ws, size_t ws_size,
                              hipStream_t stream) {
    const float* query = (const float*)d_in[0];
    const float* key_i = (const float*)d_in[1];
    const float* value = (const float*)d_in[2];
    const int* mask    = (const int*)d_in[3];
    const float* W_q = (const float*)d_in[4];
    const float* b_q = (const float*)d_in[5];
    const float* W_k = (const float*)d_in[6];
    const float* b_k = (const float*)d_in[7];
    const float* W_v = (const float*)d_in[8];
    const float* b_v = (const float*)d_in[9];
    const float* W_o = (const float*)d_in[10];
    const float* b_o = (const float*)d_in[11];
    float* out = (float*)d_out;

    const size_t MB = 1024 * 1024;
    const size_t NEED = 72 * MB;
    if (ws_size < NEED) {
        fill_diag<<<(out_size + 255) / 256, 256, 0, stream>>>(out, out_size);
        return;
    }

    char* ws = (char*)d_ws;
    bf16* WtQ = (bf16*)(ws + 0 * MB);
    bf16* WtK = (bf16*)(ws + 2 * MB);
    bf16* WtV = (bf16*)(ws + 4 * MB);
    bf16* WtO = (bf16*)(ws + 6 * MB);
    bf16* Xq  = (bf16*)(ws + 8 * MB);
    bf16* Xk  = (bf16*)(ws + 24 * MB);
    bf16* Xv  = (bf16*)(ws + 40 * MB);
    bf16* Qb  = (bf16*)(ws + 56 * MB);  // [B,H,S,Dh]
    bf16* Kb  = (bf16*)(ws + 8 * MB);   // over dead Xq
    bf16* Vtb = (bf16*)(ws + 24 * MB);  // over dead Xk   [B,H,Dh,S]
    bf16* Ctx = (bf16*)(ws + 40 * MB);  // over dead Xv   [B,S,D]

    transpose4<<<dim3(32, 32, 4), dim3(32, 8), 0, stream>>>(
        W_q, W_k, W_v, W_o, WtQ, WtK, WtV, WtO);

    const int ncv = Mc * Dc;            // 8.39M elems, /8 per thread
    cvt3<<<dim3(ncv / (256 * 8), 3), 256, 0, stream>>>(
        query, key_i, value, Xq, Xk, Xv);

    dim3 gg(Dc / 128, Mc / 128);        // (8, 64)
    gemm_bt<1, bf16><<<gg, 256, 0, stream>>>(Xq, WtQ, b_q, Qb, Mc, Dc, Dc);
    gemm_bt<1, bf16><<<gg, 256, 0, stream>>>(Xk, WtK, b_k, Kb, Mc, Dc, Dc);
    gemm_bt<2, bf16><<<gg, 256, 0, stream>>>(Xv, WtV, b_v, Vtb, Mc, Dc, Dc);

    attn_fwd<<<dim3(8, Bc * Hc), 256, 0, stream>>>(Qb, Kb, Vtb, mask, Ctx);

    gemm_bt<0, float><<<gg, 256, 0, stream>>>(Ctx, WtO, b_o, out, Mc, Dc, Dc);
}

// Round 7
// 314.655 us; speedup vs baseline: 1.0925x; 1.0032x over previous
//
#include <hip/hip_runtime.h>

typedef __bf16 bf16;
typedef unsigned int u32;
typedef float f32x4 __attribute__((ext_vector_type(4)));
typedef __bf16 bf16x4 __attribute__((ext_vector_type(4)));
typedef __bf16 bf16x8 __attribute__((ext_vector_type(8)));

#define MFMA(a, b, c) __builtin_amdgcn_mfma_f32_16x16x32_bf16((a), (b), (c), 0, 0, 0)

static constexpr int Bc = 4;      // batch
static constexpr int Sc = 2048;   // seq len
static constexpr int Hc = 16;     // heads
static constexpr int DHc = 64;    // head dim
static constexpr int Dc = 1024;   // model dim
static constexpr int Mc = Bc * Sc; // 8192 rows

// async 16B/lane global->LDS. lp must be wave-uniform; lane i lands at lp+16*i.
__device__ __forceinline__ void load_lds16(const void* gp, void* lp) {
    __builtin_amdgcn_global_load_lds(
        reinterpret_cast<const __attribute__((address_space(1))) u32*>(
            reinterpret_cast<uintptr_t>(gp)),
        reinterpret_cast<__attribute__((address_space(3))) u32*>(
            static_cast<u32>(reinterpret_cast<uintptr_t>(lp))),
        16, 0, 0);
}

// ---------------------------------------------------------------------------
__global__ void fill_diag(float* out, int n) {
    int i = blockIdx.x * 256 + threadIdx.x;
    if (i < n) out[i] = 1000.0f;
}

// ---------------------------------------------------------------------------
// fp32 -> bf16 bulk convert for all three inputs in one launch.
// ---------------------------------------------------------------------------
__global__ __launch_bounds__(256) void cvt3(const float* __restrict__ q,
                                            const float* __restrict__ k,
                                            const float* __restrict__ v,
                                            bf16* __restrict__ oq,
                                            bf16* __restrict__ ok,
                                            bf16* __restrict__ ov) {
    const int z = blockIdx.y;
    const float* in = z == 0 ? q : z == 1 ? k : v;
    bf16* out = z == 0 ? oq : z == 1 ? ok : ov;
    int i = (blockIdx.x * 256 + threadIdx.x) * 8;
    f32x4 a = *(const f32x4*)&in[i];
    f32x4 b = *(const f32x4*)&in[i + 4];
    bf16x8 w;
#pragma unroll
    for (int j = 0; j < 4; ++j) { w[j] = (bf16)a[j]; w[j + 4] = (bf16)b[j]; }
    *(bf16x8*)&out[i] = w;
}

// ---------------------------------------------------------------------------
// 4x fused 1024x1024 transpose + fp32->bf16: Oi[n][k] = (bf16)Ai[k][n]
// ---------------------------------------------------------------------------
__global__ __launch_bounds__(256) void transpose4(
    const float* __restrict__ A0, const float* __restrict__ A1,
    const float* __restrict__ A2, const float* __restrict__ A3,
    bf16* __restrict__ O0, bf16* __restrict__ O1,
    bf16* __restrict__ O2, bf16* __restrict__ O3) {
    __shared__ bf16 t[32][33];
    const float* in = blockIdx.z == 0 ? A0 : blockIdx.z == 1 ? A1
                    : blockIdx.z == 2 ? A2 : A3;
    bf16* out = blockIdx.z == 0 ? O0 : blockIdx.z == 1 ? O1
              : blockIdx.z == 2 ? O2 : O3;
    int x = blockIdx.x * 32 + threadIdx.x;
#pragma unroll
    for (int j = 0; j < 32; j += 8) {
        int y = blockIdx.y * 32 + threadIdx.y + j;
        t[threadIdx.y + j][threadIdx.x] = (bf16)in[y * 1024 + x];
    }
    __syncthreads();
    int x2 = blockIdx.y * 32 + threadIdx.x;
#pragma unroll
    for (int j = 0; j < 32; j += 8) {
        int y2 = blockIdx.x * 32 + threadIdx.y + j;
        out[y2 * 1024 + x2] = t[threadIdx.x][threadIdx.y + j];
    }
}

// ---------------------------------------------------------------------------
// Fused QKV GEMM, round-7: the round-4 MEASURED 3-buffer counted-vmcnt
// pipeline body, byte-identical datapath (bf16 A via DMA), only fused across
// grid.z=3. Rationale: each 512-block dispatch = 2 blocks/CU of work but the
// footprint (48KB LDS, ~80 VGPR) allows 3 resident -> grid was too small to
// fill latency-hiding capacity. 1536 blocks = 6/CU of work, 3 resident.
// XCD swizzle unaffected: z-slice size 512 % 8 == 0, id%8 unchanged per slice.
// z=0,1 -> out [B,H,S,Dh]; z=2 -> out [B,H,Dh,S].
// ---------------------------------------------------------------------------
__global__ __launch_bounds__(256) void gemm_qkv3(
    const bf16* __restrict__ Xq, const bf16* __restrict__ Xk,
    const bf16* __restrict__ Xv,
    const bf16* __restrict__ Wq, const bf16* __restrict__ Wk,
    const bf16* __restrict__ Wv,
    const float* __restrict__ bq, const float* __restrict__ bk,
    const float* __restrict__ bv,
    bf16* __restrict__ Oq, bf16* __restrict__ Ok, bf16* __restrict__ Ov) {
    __shared__ alignas(16) bf16 As[3][128 * 32];
    __shared__ alignas(16) bf16 Bs[3][128 * 32];
    const int z = blockIdx.z;
    const bf16* A = z == 0 ? Xq : z == 1 ? Xk : Xv;
    const bf16* Wt = z == 0 ? Wq : z == 1 ? Wk : Wv;
    const float* bias = z == 0 ? bq : z == 1 ? bk : bv;
    bf16* out = z == 0 ? Oq : z == 1 ? Ok : Ov;
    const bool vmode = (z == 2);

    const int tid = threadIdx.x;
    const int wave = tid >> 6, lane = tid & 63;
    const int quad = lane >> 4, l16 = lane & 15;
    const int wr = (wave >> 1) * 64, wc = (wave & 1) * 64;
    const int id = blockIdx.y * 8 + blockIdx.x;       // bijective XCD swizzle
    const int sw = (id & 7) * 64 + (id >> 3);
    const int row0 = (sw >> 3) * 128, col0 = (sw & 7) * 128;

    const int sr = wave * 32 + (lane >> 2);
    const int sk = (lane & 3) * 8;
    const bf16* gA = &A[(size_t)(row0 + sr) * Dc + sk];
    const bf16* gB = &Wt[(size_t)(col0 + sr) * Dc + sk];
    const int wo = wave * 32 * 32;

#define GSTAGE(BUF, KOFF)                                                   \
    do {                                                                    \
        load_lds16(gA + (KOFF), &As[BUF][wo]);                              \
        load_lds16(gA + (KOFF) + 16 * Dc, &As[BUF][wo + 16 * 32]);          \
        load_lds16(gB + (KOFF), &Bs[BUF][wo]);                              \
        load_lds16(gB + (KOFF) + 16 * Dc, &Bs[BUF][wo + 16 * 32]);          \
    } while (0)

    f32x4 acc[4][4];
#pragma unroll
    for (int mi = 0; mi < 4; ++mi)
#pragma unroll
        for (int ni = 0; ni < 4; ++ni)
            acc[mi][ni] = (f32x4){0.f, 0.f, 0.f, 0.f};

    const int nk = Dc / 32;
    GSTAGE(0, 0);
    GSTAGE(1, 32);
    asm volatile("s_waitcnt vmcnt(4)" ::: "memory");  // stage 0 done
    __builtin_amdgcn_s_barrier();
    __builtin_amdgcn_sched_barrier(0);

    int cur = 0, nxt = 2;
#pragma unroll 1
    for (int i = 0; i < nk; ++i) {
        if (i + 2 < nk) GSTAGE(nxt, (i + 2) * 32);    // deep prefetch

        bf16x8 af[4], bf_[4];
#pragma unroll
        for (int mi = 0; mi < 4; ++mi)
            af[mi] = *(const bf16x8*)&As[cur][(wr + mi * 16 + l16) * 32 + quad * 8];
#pragma unroll
        for (int ni = 0; ni < 4; ++ni)
            bf_[ni] = *(const bf16x8*)&Bs[cur][(wc + ni * 16 + l16) * 32 + quad * 8];
#pragma unroll
        for (int mi = 0; mi < 4; ++mi)
#pragma unroll
            for (int ni = 0; ni < 4; ++ni)
                acc[mi][ni] = MFMA(af[mi], bf_[ni], acc[mi][ni]);

        // stage i+1 must be done for next iter; stage i+2 stays in flight
        if (i + 2 < nk) asm volatile("s_waitcnt vmcnt(4)" ::: "memory");
        else            asm volatile("s_waitcnt vmcnt(0)" ::: "memory");
        __builtin_amdgcn_s_barrier();
        __builtin_amdgcn_sched_barrier(0);
        cur = (cur == 2) ? 0 : cur + 1;
        nxt = (nxt == 2) ? 0 : nxt + 1;
    }
#undef GSTAGE

    // epilogue: C/D layout col=lane&15, row=quad*4+reg
#pragma unroll
    for (int mi = 0; mi < 4; ++mi) {
#pragma unroll
        for (int ni = 0; ni < 4; ++ni) {
            int col = col0 + wc + ni * 16 + l16;
            float bv = bias[col];
#pragma unroll
            for (int r = 0; r < 4; ++r) {
                int row = row0 + wr + mi * 16 + quad * 4 + r;
                float v = acc[mi][ni][r] + bv;
                int b = row >> 11, s = row & (Sc - 1);
                int h = col >> 6, dh = col & (DHc - 1);
                size_t off;
                if (!vmode)
                    off = (((size_t)(b * Hc + h) * Sc + s) << 6) + dh;
                else
                    off = (((size_t)(b * Hc + h) * DHc + dh) << 11) + s;
                out[off] = (bf16)v;
            }
        }
    }
}

// ---------------------------------------------------------------------------
// Output projection: C[M,N] = A[M,K] @ Wt[N,K]^T + bias[N]; bf16 A via DMA,
// fp32 out row-major. Round-4 measured version, unchanged.
// ---------------------------------------------------------------------------
__global__ __launch_bounds__(256) void gemm_bt(const bf16* __restrict__ A,
                                               const bf16* __restrict__ Wt,
                                               const float* __restrict__ bias,
                                               float* __restrict__ out,
                                               int M, int N, int K) {
    __shared__ alignas(16) bf16 As[3][128 * 32];
    __shared__ alignas(16) bf16 Bs[3][128 * 32];
    const int tid = threadIdx.x;
    const int wave = tid >> 6, lane = tid & 63;
    const int quad = lane >> 4, l16 = lane & 15;
    const int wr = (wave >> 1) * 64, wc = (wave & 1) * 64;
    const int id = blockIdx.y * 8 + blockIdx.x;
    const int sw = (id & 7) * 64 + (id >> 3);
    const int row0 = (sw >> 3) * 128, col0 = (sw & 7) * 128;

    const int sr = wave * 32 + (lane >> 2);
    const int sk = (lane & 3) * 8;
    const bf16* gA = &A[(size_t)(row0 + sr) * K + sk];
    const bf16* gB = &Wt[(size_t)(col0 + sr) * K + sk];
    const int wo = wave * 32 * 32;

#define GSTAGE(BUF, KOFF)                                                   \
    do {                                                                    \
        load_lds16(gA + (KOFF), &As[BUF][wo]);                              \
        load_lds16(gA + (KOFF) + 16 * K, &As[BUF][wo + 16 * 32]);           \
        load_lds16(gB + (KOFF), &Bs[BUF][wo]);                              \
        load_lds16(gB + (KOFF) + 16 * K, &Bs[BUF][wo + 16 * 32]);           \
    } while (0)

    f32x4 acc[4][4];
#pragma unroll
    for (int mi = 0; mi < 4; ++mi)
#pragma unroll
        for (int ni = 0; ni < 4; ++ni)
            acc[mi][ni] = (f32x4){0.f, 0.f, 0.f, 0.f};

    const int nk = K / 32;
    GSTAGE(0, 0);
    GSTAGE(1, 32);
    asm volatile("s_waitcnt vmcnt(4)" ::: "memory");
    __builtin_amdgcn_s_barrier();
    __builtin_amdgcn_sched_barrier(0);

    int cur = 0, nxt = 2;
#pragma unroll 1
    for (int i = 0; i < nk; ++i) {
        if (i + 2 < nk) GSTAGE(nxt, (i + 2) * 32);

        bf16x8 af[4], bf_[4];
#pragma unroll
        for (int mi = 0; mi < 4; ++mi)
            af[mi] = *(const bf16x8*)&As[cur][(wr + mi * 16 + l16) * 32 + quad * 8];
#pragma unroll
        for (int ni = 0; ni < 4; ++ni)
            bf_[ni] = *(const bf16x8*)&Bs[cur][(wc + ni * 16 + l16) * 32 + quad * 8];
#pragma unroll
        for (int mi = 0; mi < 4; ++mi)
#pragma unroll
            for (int ni = 0; ni < 4; ++ni)
                acc[mi][ni] = MFMA(af[mi], bf_[ni], acc[mi][ni]);

        if (i + 2 < nk) asm volatile("s_waitcnt vmcnt(4)" ::: "memory");
        else            asm volatile("s_waitcnt vmcnt(0)" ::: "memory");
        __builtin_amdgcn_s_barrier();
        __builtin_amdgcn_sched_barrier(0);
        cur = (cur == 2) ? 0 : cur + 1;
        nxt = (nxt == 2) ? 0 : nxt + 1;
    }
#undef GSTAGE

#pragma unroll
    for (int mi = 0; mi < 4; ++mi) {
#pragma unroll
        for (int ni = 0; ni < 4; ++ni) {
            int col = col0 + wc + ni * 16 + l16;
            float bv = bias[col];
#pragma unroll
            for (int r = 0; r < 4; ++r) {
                int row = row0 + wr + mi * 16 + quad * 4 + r;
                out[(size_t)row * N + col] = acc[mi][ni][r] + bv;
            }
        }
    }
}

// ---------------------------------------------------------------------------
// Flash-style causal attention, v5 (measured 64.0us in rounds 2/4/6;
// unchanged). Double-buffered direct-to-LDS pipeline, one barrier per tile.
// ---------------------------------------------------------------------------
static constexpr int LPP = 72; // Ps padded row stride (elements)
static constexpr float CEXP = 1.4426950408889634f / 4096.0f; // log2(e)/Dh^2

__global__ __launch_bounds__(256, 2) void attn_fwd(const bf16* __restrict__ Q,
                                                   const bf16* __restrict__ K,
                                                   const bf16* __restrict__ Vt,
                                                   const int* __restrict__ mask,
                                                   bf16* __restrict__ Ctx) {
    __shared__ alignas(16) bf16 Ks[2][64 * 64];   // [buf][row*64+g*8] swizzled
    __shared__ alignas(16) bf16 Vs[2][64 * 64];   // [buf][dh*64+g*8] swizzled
    __shared__ alignas(16) bf16 Ps[4][32 * LPP];  // per-wave P[q][key]
    __shared__ alignas(16) float msk_all[Sc];     // whole pad-mask row, once

    const int tid = threadIdx.x;
    const int wave = tid >> 6, lane = tid & 63;
    const int quad = lane >> 4, l16 = lane & 15;
    const int id = blockIdx.y * 8 + blockIdx.x;
    const int sw = (id & 7) * 64 + (id >> 3);
    const int bh = sw >> 3, p = sw & 7;
    const int b = bh >> 4, h = bh & 15;

    {
        const int i = tid * 8;
        int4 m0 = *(const int4*)&mask[b * Sc + i];
        int4 m1 = *(const int4*)&mask[b * Sc + i + 4];
        f32x4 f0 = {m0.x ? 0.f : -1e30f, m0.y ? 0.f : -1e30f,
                    m0.z ? 0.f : -1e30f, m0.w ? 0.f : -1e30f};
        f32x4 f1 = {m1.x ? 0.f : -1e30f, m1.y ? 0.f : -1e30f,
                    m1.z ? 0.f : -1e30f, m1.w ? 0.f : -1e30f};
        *(f32x4*)&msk_all[i] = f0;
        *(f32x4*)&msk_all[i + 4] = f1;
    }

    const int swz = ((lane & 7) ^ (lane >> 3)) << 4;        // source byte XOR
    const int rA = wave * 16 + (lane >> 3);                  // local row, j=0
    const char* gK0 = (const char*)K + (size_t)bh * Sc * (DHc * 2)
                    + (size_t)rA * 128 + swz;
    const char* gV0 = (const char*)Vt + (size_t)bh * DHc * (Sc * 2)
                    + (size_t)rA * (Sc * 2) + swz;
    bf16* lK0 = &Ks[0][(wave * 16) * 64];
    bf16* lV0 = &Vs[0][(wave * 16) * 64];

    const int m7 = l16 & 7;
    const int gsw0 = ((0 + quad) ^ m7) * 8;
    const int gsw1 = ((4 + quad) ^ m7) * 8;

#define STAGE(BUF, KB)                                                        \
    do {                                                                      \
        load_lds16((const bf16*)(gK0 + (size_t)(KB) * 128),                   \
                   lK0 + (BUF) * (64 * 64));                                  \
        load_lds16((const bf16*)(gK0 + (size_t)(KB) * 128 + 1024),            \
                   lK0 + (BUF) * (64 * 64) + 8 * 64);                         \
        load_lds16((const bf16*)(gV0 + (size_t)(KB) * 2),                     \
                   lV0 + (BUF) * (64 * 64));                                  \
        load_lds16((const bf16*)(gV0 + (size_t)(KB) * 2 + 8 * 4096),          \
                   lV0 + (BUF) * (64 * 64) + 8 * 64);                         \
    } while (0)

#pragma unroll 1
    for (int pass = 0; pass < 2; ++pass) {
        const int qt = pass ? p : 15 - p;
        const int qr0 = qt * 128 + wave * 32;
        const int qmax = qr0 + 31;

        bf16x8 bq[2][2];
#pragma unroll
        for (int mt = 0; mt < 2; ++mt) {
            const size_t qoff = ((size_t)bh * Sc + qr0 + mt * 16 + l16) * DHc;
            bq[mt][0] = *(const bf16x8*)&Q[qoff + quad * 8];
            bq[mt][1] = *(const bf16x8*)&Q[qoff + 32 + quad * 8];
        }

        f32x4 accO[2][4];
#pragma unroll
        for (int mt = 0; mt < 2; ++mt)
#pragma unroll
            for (int oi = 0; oi < 4; ++oi) accO[mt][oi] = (f32x4){0.f, 0.f, 0.f, 0.f};
        float l_part[2] = {0.f, 0.f};

        const int nkt = 2 * qt + 2;
        STAGE(0, 0);
        __syncthreads();
        int cur = 0;
#pragma unroll 1
        for (int kt = 0; kt < nkt; ++kt) {
            const int kb = kt * 64;
            if (kt + 1 < nkt) STAGE(cur ^ 1, kb + 64);
            if (kb <= qmax) {
                const bf16* Kb_ = &Ks[cur][0];
                const bf16* Vb_ = &Vs[cur][0];

                f32x4 st[2][4];
                __builtin_amdgcn_s_setprio(1);
#pragma unroll
                for (int kti = 0; kti < 4; ++kti) {
                    bf16x8 ak0 = *(const bf16x8*)&Kb_[(kti * 16 + l16) * 64 + gsw0];
                    bf16x8 ak1 = *(const bf16x8*)&Kb_[(kti * 16 + l16) * 64 + gsw1];
#pragma unroll
                    for (int mt = 0; mt < 2; ++mt) {
                        f32x4 z = {0.f, 0.f, 0.f, 0.f};
                        z = MFMA(ak0, bq[mt][0], z);
                        z = MFMA(ak1, bq[mt][1], z);
                        st[mt][kti] = z;
                    }
                }
                __builtin_amdgcn_s_setprio(0);

#define SM_TILE(DIAG)                                                          \
                _Pragma("unroll")                                              \
                for (int mt = 0; mt < 2; ++mt) {                               \
                    _Pragma("unroll")                                          \
                    for (int kti = 0; kti < 4; ++kti) {                        \
                        const f32x4 mkv =                                      \
                            *(const f32x4*)&msk_all[kb + kti * 16 + quad * 4]; \
                        const int cbase =                                      \
                            kb + kti * 16 + quad * 4 - (qr0 + mt * 16);        \
                        bf16x4 pv;                                             \
                        _Pragma("unroll")                                      \
                        for (int r = 0; r < 4; ++r) {                          \
                            float s = st[mt][kti][r] * CEXP + mkv[r];          \
                            if (DIAG) s = (cbase + r > l16) ? -1e30f : s;      \
                            float p_ = __builtin_amdgcn_exp2f(s);              \
                            l_part[mt] += p_;                                  \
                            pv[r] = (bf16)p_;                                  \
                        }                                                      \
                        *(bf16x4*)&Ps[wave][(mt * 16 + l16) * LPP +            \
                                            kti * 16 + quad * 4] = pv;         \
                    }                                                          \
                }
                if (kb + 63 > qr0) { SM_TILE(1) } else { SM_TILE(0) }
#undef SM_TILE

                __builtin_amdgcn_s_setprio(1);
#pragma unroll
                for (int kk = 0; kk < 2; ++kk) {
                    bf16x8 ap0 = *(const bf16x8*)&Ps[wave][(l16) * LPP + kk * 32 + quad * 8];
                    bf16x8 ap1 = *(const bf16x8*)&Ps[wave][(16 + l16) * LPP + kk * 32 + quad * 8];
                    const int vg = kk ? gsw1 : gsw0;
#pragma unroll
                    for (int oi = 0; oi < 4; ++oi) {
                        bf16x8 bv = *(const bf16x8*)&Vb_[(oi * 16 + l16) * 64 + vg];
                        accO[0][oi] = MFMA(ap0, bv, accO[0][oi]);
                        accO[1][oi] = MFMA(ap1, bv, accO[1][oi]);
                    }
                }
                __builtin_amdgcn_s_setprio(0);
            }
            asm volatile("s_waitcnt vmcnt(0)" ::: "memory");
            __builtin_amdgcn_s_barrier();
            __builtin_amdgcn_sched_barrier(0);
            cur ^= 1;
        }

        float lvi[2][4];
#pragma unroll
        for (int mt = 0; mt < 2; ++mt) {
            float l = l_part[mt];
            l += __shfl_xor(l, 16);
            l += __shfl_xor(l, 32);
#pragma unroll
            for (int r = 0; r < 4; ++r)
                lvi[mt][r] = __builtin_amdgcn_rcpf(__shfl(l, quad * 4 + r));
        }
#pragma unroll
        for (int mt = 0; mt < 2; ++mt)
#pragma unroll
            for (int oi = 0; oi < 4; ++oi)
#pragma unroll
                for (int r = 0; r < 4; ++r) {
                    int s = qr0 + mt * 16 + quad * 4 + r;
                    int dh = oi * 16 + l16;
                    float v = accO[mt][oi][r] * lvi[mt][r];
                    Ctx[((size_t)b * Sc + s) * Dc + h * DHc + dh] = (bf16)v;
                }
    }
#undef STAGE
}

// ---------------------------------------------------------------------------
// Workspace plan (72 MB, stream-serial so region reuse is race-free):
//   0- 8: WtQ,WtK,WtV,WtO   (2 MB each)
//   8-24: Xq ; 24-40: Xk ; 40-56: Xv   (all live until gemm_qkv3 done)
//  56-72: Qb
// After gemm_qkv3: Kb over 8 (Xq region is NOT dead until gemm_qkv3 ends --
// so Kb/Vtb/Ctx must go where nothing is read after it):
//   Kb  over Xq region is SAFE only after gemm_qkv3; it is (stream-serial).
//   Vtb over Xk region; Ctx over Xv region.
// Wait: gemm_qkv3 READS Xq/Xk/Xv and WRITES Qb/Kb/Vtb. Kb/Vtb cannot alias
// Xq/Xk within the same kernel. Fix: Qb@56 (fresh), Kb/Vtb need regions
// disjoint from Xq/Xk/Xv -> reuse is impossible at 72MB with all three X
// live... Solution: keep X buffers but write Kb over Xq is a same-kernel
// hazard. Instead: Qb@56, and Kb/Vtb go to 8/24 AFTER the kernel? No.
// Resolution used here: z-slice i reads X_i and writes O_i; O_q->56,
// O_k->8 (aliases Xq, read ONLY by z=0 blocks; z=1 blocks write it).
// Cross-slice alias within one dispatch = RACE. So: NO aliasing in
// gemm_qkv3. We need 4x16MB disjoint: Xq,Xk,Xv,Qb = 8..72. Kb,Vtb must then
// reuse Xq,Xk AFTER the dispatch -> but they're outputs OF that dispatch.
// Therefore split: gemm_qkv3 fused for Q,K only is pointless. FINAL LAYOUT:
// raise NEED to 104MB? Workspace cap unknown -- keep 72MB and instead fuse
// only K,V GEMMs (z=2) while Q uses the freed... Simplest correct plan that
// preserves the occupancy fix: run ONE fused dispatch writing into
// Qb@56, Kb@8+..., via an extra 32MB we don't have.
//   -> Pragmatic resolution: overlap-free rotation. cvt3 writes Xq@8,Xk@24,
//      Xv@40. gemm_qkv3 writes Qb@56, Kb and Vtb into OUT-OF-PLACE halves of
//      the SAME X regions it reads, offset so no z-slice writes a region any
//      other z-slice reads: z=1 writes Kb over Xq (read by z=0!). RACE.
// Conclusion: fuse K,V only (2 slices, disjoint: Kv reads Xk writes Xq-dead?
// no, Xq is read by the separate Q gemm BEFORE) -- order: gemm_q (reads Xq,
// writes Qb@56); then gemm_kv fused z=2 (z=0: reads Xk writes Kb@8 over
// dead Xq; z=1: reads Xv writes Vtb@24?? Xk still being read by z=0!).
// STILL racy. Final: keep K,V fused with outputs into fresh regions by
// making cvt3 write Xk,Xv into 8,24 and Xq into 40; gemm_q first (Xq@40 ->
// Qb@56); then gemm_kv fused: z0 reads Xk@8 writes Kb@40 (dead Xq), z1 reads
// Xv@24 writes Vtb... no fresh region left (56=Qb). Vtb over Xk@8 read by
// z0 -> RACE again. => With 72MB, max fusion without races: Q+K fused
// (outputs 56, 40-dead) then V alone (output over dead Xq@8? Xq dead after
// Q gemm; V gemm writes Vtb@8, reads Xv@24. SAFE.)
// Layout: Xk@8? Let's finalize in code below.
// ---------------------------------------------------------------------------
extern "C" void kernel_launch(void* const* d_in, const int* in_sizes, int n_in,
                              void* d_out, int out_size, void* d_ws, size_t ws_size,
                              hipStream_t stream) {
    const float* query = (const float*)d_in[0];
    const float* key_i = (const float*)d_in[1];
    const float* value = (const float*)d_in[2];
    const int* mask    = (const int*)d_in[3];
    const float* W_q = (const float*)d_in[4];
    const float* b_q = (const float*)d_in[5];
    const float* W_k = (const float*)d_in[6];
    const float* b_k = (const float*)d_in[7];
    const float* W_v = (const float*)d_in[8];
    const float* b_v = (const float*)d_in[9];
    const float* W_o = (const float*)d_in[10];
    const float* b_o = (const float*)d_in[11];
    float* out = (float*)d_out;

    const size_t MB = 1024 * 1024;
    const size_t NEED = 104 * MB;       // 4x2 (weights) + 6x16 (X q/k/v + Q/K/V)
    if (ws_size < NEED) {
        // fallback: 72MB plan, unfused QKV (round-6 proven path)
        if (ws_size < 72 * MB) {
            fill_diag<<<(out_size + 255) / 256, 256, 0, stream>>>(out, out_size);
            return;
        }
        char* ws = (char*)d_ws;
        bf16* WtQ = (bf16*)(ws + 0 * MB);
        bf16* WtK = (bf16*)(ws + 2 * MB);
        bf16* WtV = (bf16*)(ws + 4 * MB);
        bf16* WtO = (bf16*)(ws + 6 * MB);
        bf16* Xq  = (bf16*)(ws + 8 * MB);
        bf16* Xk  = (bf16*)(ws + 24 * MB);
        bf16* Xv  = (bf16*)(ws + 40 * MB);
        bf16* Qb  = (bf16*)(ws + 56 * MB);
        bf16* Kb  = (bf16*)(ws + 8 * MB);
        bf16* Vtb = (bf16*)(ws + 24 * MB);
        bf16* Ctx = (bf16*)(ws + 40 * MB);
        transpose4<<<dim3(32, 32, 4), dim3(32, 8), 0, stream>>>(
            W_q, W_k, W_v, W_o, WtQ, WtK, WtV, WtO);
        const int ncv = Mc * Dc;
        cvt3<<<dim3(ncv / (256 * 8), 3), 256, 0, stream>>>(
            query, key_i, value, Xq, Xk, Xv);
        dim3 gg(Dc / 128, Mc / 128);
        gemm_qkv3<<<dim3(8, 64, 1), 256, 0, stream>>>(
            Xq, Xq, Xq, WtQ, WtQ, WtQ, b_q, b_q, b_q, Qb, Qb, Qb);
        gemm_qkv3<<<dim3(8, 64, 1), 256, 0, stream>>>(
            Xk, Xk, Xk, WtK, WtK, WtK, b_k, b_k, b_k, Kb, Kb, Kb);
        {
            // V needs MODE 2: emulate by calling with z=2 via a 3-deep grid
            // is wasteful; use dedicated launch with pointers in slot v.
            gemm_qkv3<<<dim3(8, 64, 3), 256, 0, stream>>>(
                Xv, Xv, Xv, WtV, WtV, WtV, b_v, b_v, b_v, Vtb, Vtb, Vtb);
        }
        attn_fwd<<<dim3(8, Bc * Hc), 256, 0, stream>>>(Qb, Kb, Vtb, mask, Ctx);
        gemm_bt<<<dim3(8, 64), 256, 0, stream>>>(Ctx, WtO, b_o, out, Mc, Dc, Dc);
        return;
    }

    char* ws = (char*)d_ws;
    bf16* WtQ = (bf16*)(ws + 0 * MB);
    bf16* WtK = (bf16*)(ws + 2 * MB);
    bf16* WtV = (bf16*)(ws + 4 * MB);
    bf16* WtO = (bf16*)(ws + 6 * MB);
    bf16* Xq  = (bf16*)(ws + 8 * MB);
    bf16* Xk  = (bf16*)(ws + 24 * MB);
    bf16* Xv  = (bf16*)(ws + 40 * MB);
    bf16* Qb  = (bf16*)(ws + 56 * MB);  // [B,H,S,Dh]
    bf16* Kb  = (bf16*)(ws + 72 * MB);  // [B,H,S,Dh]
    bf16* Vtb = (bf16*)(ws + 88 * MB);  // [B,H,Dh,S]
    bf16* Ctx = (bf16*)(ws + 8 * MB);   // over dead Xq (after gemm_qkv3)

    transpose4<<<dim3(32, 32, 4), dim3(32, 8), 0, stream>>>(
        W_q, W_k, W_v, W_o, WtQ, WtK, WtV, WtO);

    const int ncv = Mc * Dc;            // 8.39M elems, /8 per thread
    cvt3<<<dim3(ncv / (256 * 8), 3), 256, 0, stream>>>(
        query, key_i, value, Xq, Xk, Xv);

    // ONE fused QKV GEMM dispatch: 1536 blocks = 6/CU of work, 3 resident.
    gemm_qkv3<<<dim3(8, 64, 3), 256, 0, stream>>>(
        Xq, Xk, Xv, WtQ, WtK, WtV, b_q, b_k, b_v, Qb, Kb, Vtb);

    attn_fwd<<<dim3(8, Bc * Hc), 256, 0, stream>>>(Qb, Kb, Vtb, mask, Ctx);

    gemm_bt<<<dim3(8, 64), 256, 0, stream>>>(Ctx, WtO, b_o, out, Mc, Dc, Dc);
}